// Round 18
// baseline (2859.727 us; speedup 1.0000x reference)
//
#include <hip/hip_runtime.h>
#include <hip/hip_bf16.h>

#define DI 1536
#define DS 16
#define DC 4
#define DTR 48
#define NB 2
#define SL 1024
#define DM 768
#define NLAYER 12
#define VOCAB 50257
#define ROWS (NB*SL)   // 2048
#define CCH 32         // scan chunks
#define CLEN (SL/CCH)  // 32
#define NBIG (DI+32)   // 1568: fused dt(1536) + B/C(32) outputs

typedef __attribute__((ext_vector_type(8))) short bf16x8;
typedef __attribute__((ext_vector_type(4))) short short4v;
typedef __attribute__((ext_vector_type(4))) float f32x4;

__device__ inline short f2bf(float f) {
    unsigned u = __builtin_bit_cast(unsigned, f);
    unsigned r = (u + 0x7fffu + ((u >> 16) & 1u)) >> 16;
    return (short)r;
}
__device__ inline float bf2f(unsigned short u) {
    unsigned x = ((unsigned)u) << 16;
    return __builtin_bit_cast(float, x);
}

__device__ __forceinline__ void gl_lds16(const void* g, void* l) {
    __builtin_amdgcn_global_load_lds(
        (const __attribute__((address_space(1))) unsigned int*)g,
        (__attribute__((address_space(3))) unsigned int*)l, 16, 0, 0);
}

// ---------------------------------------------------------------------------
// fp32 -> bf16 convert for 3 arrays in one dispatch (each n multiple of 4)
// ---------------------------------------------------------------------------
__global__ __launch_bounds__(256) void cvt3_k(
    const float* __restrict__ s0, unsigned short* __restrict__ d0, int n40,
    const float* __restrict__ s1, unsigned short* __restrict__ d1, int n41,
    const float* __restrict__ s2, unsigned short* __restrict__ d2, int n42)
{
    int i = blockIdx.x * 256 + threadIdx.x;
    const float* src; unsigned short* dst;
    if (i < n40) { src = s0; dst = d0; }
    else if (i < n40 + n41) { i -= n40; src = s1; dst = d1; }
    else if (i < n40 + n41 + n42) { i -= n40 + n41; src = s2; dst = d2; }
    else return;
    float4 v = *reinterpret_cast<const float4*>(src + (size_t)i * 4);
    short4v o;
    o[0] = f2bf(v.x); o[1] = f2bf(v.y); o[2] = f2bf(v.z); o[3] = f2bf(v.w);
    *reinterpret_cast<short4v*>(dst + (size_t)i * 4) = o;
}

// ---------------------------------------------------------------------------
// Wc precompute: wbig[l] rows 0..1535 = dtw @ xpw[:48]  (bf16),
//                rows 1536..1567 = xpw[48:80] (bf16).
// ---------------------------------------------------------------------------
__global__ __launch_bounds__(256) void wc_k(
    const float* __restrict__ dtw_all,   // (NL, DI, DTR)
    const float* __restrict__ xpw_all,   // (NL, 80, DI)
    unsigned short* __restrict__ wbig)   // (NL, NBIG, DI)
{
    int l = blockIdx.z;
    const float* dtw = dtw_all + (size_t)l * DI * DTR;
    const float* xpw = xpw_all + (size_t)l * 80 * DI;
    unsigned short* wb = wbig + (size_t)l * NBIG * DI;
    int tid = threadIdx.x;
    if (blockIdx.y == 12) {
        if (blockIdx.x == 0) {
            for (int idx = tid; idx < 32 * DI; idx += 256) {
                int rr = idx / DI, k = idx - rr * DI;
                wb[(size_t)(DI + rr) * DI + k] =
                    (unsigned short)f2bf(xpw[(size_t)(48 + rr) * DI + k]);
            }
        }
        return;
    }
    __shared__ float sd[128 * 48];
    __shared__ float sx[48 * 128];
    int d0 = blockIdx.y * 128, k0 = blockIdx.x * 128;
    for (int idx = tid; idx < 128 * 48; idx += 256) {
        int r = idx / 48, j = idx - r * 48;
        sd[idx] = dtw[(size_t)(d0 + r) * DTR + j];
    }
    for (int idx = tid; idx < 48 * 128; idx += 256) {
        int j = idx / 128, k = idx - j * 128;
        sx[idx] = xpw[(size_t)j * DI + k0 + k];
    }
    __syncthreads();
    int tx = tid & 15, ty = tid >> 4;
    float acc[8][8] = {};
    for (int j = 0; j < 48; ++j) {
        float a[8], w[8];
        #pragma unroll
        for (int i = 0; i < 8; ++i) a[i] = sd[(ty * 8 + i) * 48 + j];
        #pragma unroll
        for (int i = 0; i < 8; ++i) w[i] = sx[j * 128 + tx * 8 + i];
        #pragma unroll
        for (int i = 0; i < 8; ++i)
            #pragma unroll
            for (int jj = 0; jj < 8; ++jj)
                acc[i][jj] += a[i] * w[jj];
    }
    for (int i = 0; i < 8; ++i)
        for (int jj = 0; jj < 8; ++jj)
            wb[(size_t)(d0 + ty * 8 + i) * DI + k0 + tx * 8 + jj] =
                (unsigned short)f2bf(acc[i][jj]);
}

// ---------------------------------------------------------------------------
// Embedding (vectorized x4)
// ---------------------------------------------------------------------------
__global__ __launch_bounds__(256) void embed_k(const int* __restrict__ ids,
                                               const float* __restrict__ emb,
                                               unsigned short* __restrict__ xbf) {
    int i = blockIdx.x * 256 + threadIdx.x;      // over ROWS * DM/4
    if (i >= ROWS * (DM / 4)) return;
    int row = i / (DM / 4);
    int c4 = (i - row * (DM / 4)) * 4;
    float4 v = *reinterpret_cast<const float4*>(
        &emb[(size_t)ids[row] * DM + c4]);
    const float s = 27.712812921102035f;
    short4v o;
    o[0] = f2bf(v.x * s); o[1] = f2bf(v.y * s);
    o[2] = f2bf(v.z * s); o[3] = f2bf(v.w * s);
    *reinterpret_cast<short4v*>(&xbf[(size_t)row * DM + c4]) = o;
}

// ---------------------------------------------------------------------------
// bf16-MFMA GEMM with COUNTED vmcnt (T3/T4). Two schedule variants:
//   SB=false (dual-barrier): NBUF >= PF+1. Trailing s_barrier WAR-guards the
//            slot re-staged next iter. (Logits optimum: MT128/NBUF2/PF1.)
//   SB=true  (single-barrier): NBUF >= PF+2 so the slot staged at iter t was
//            last read at iter t-2; the iter t-1 top barrier orders it.
//            (Layer GEMMs: NBUF4/PF2.)
// BS=256 threads (4 waves 2x2), MT x 128 tile, BKT=32.
// global_load_lds staging, linear LDS dest, pre-swizzled source
// (involution chunk ^ ((row>>1)&3), conflict-free ds_read_b128).
// OUT: 0 = fp32 store (NTST -> LDS-transposed full-line NT epilogue);
//      2 = bf16-only store; 3 = fused dt softplus (bf16) / BC (fp32) split.
// ---------------------------------------------------------------------------
template<int BS, int MT, int NBUF, int PF, bool SB, int OUT, bool NTST>
__global__ __launch_bounds__(BS) void gemm_bf16(
    const unsigned short* __restrict__ A, int lda,
    const unsigned short* __restrict__ W, int ldw,
    float* __restrict__ C, unsigned short* __restrict__ Cbf, int ldc,
    int GY, int N, int K,
    const float* __restrict__ bias, float* __restrict__ aux)
{
    static_assert(SB ? (NBUF >= PF + 2) : (NBUF >= PF + 1),
                  "WAR safety: SB needs NBUF>=PF+2, dual-barrier NBUF>=PF+1");
    constexpr int BKT = 32;
    constexpr int WRG = (BS / 64) / 2;            // wr groups (2)
    constexpr int ACH = MT * (BKT / 8);           // A chunks per tile
    constexpr int ACA = (ACH >= BS) ? ACH / BS : 1;
    constexpr int ACW = (128 * (BKT / 8)) / BS;   // W staging issues/thread
    constexpr int ISS = ACA + ACW;                // gl_lds instrs per STAGE
    constexpr int MFR = MT / (16 * WRG);          // M fragments per wave
    constexpr int BUFS = (MT + 128) * BKT;        // shorts per buffer
    __shared__ __align__(16) short smem[NBUF * BUFS];

    const int tid  = threadIdx.x;
    const int lane = tid & 63;
    const int wid  = tid >> 6;
    const int wr   = wid >> 1, wc = wid & 1;

    // bijective XCD-chunked swizzle, then col-major decode
    const int nwg = gridDim.x;
    const int q = nwg >> 3, rm = nwg & 7;
    const int xcd = blockIdx.x & 7, bidx = blockIdx.x >> 3;
    const int wg = (xcd < rm ? xcd * (q + 1) : rm * (q + 1) + (xcd - rm) * q) + bidx;
    const int row0 = (wg % GY) * MT;
    const int col0 = (wg / GY) * 128;

    // ---- staging setup (pre-swizzled global sources) ----
    const unsigned short* gA[ACA];
    const unsigned short* gW[ACW];
    #pragma unroll
    for (int i = 0; i < ACA; ++i) {
        int cid = (ACH >= BS) ? (i * BS + tid) : (tid & (ACH - 1));
        int r = cid >> 2, c = cid & 3;
        gA[i] = A + (size_t)(row0 + r) * lda + ((c ^ ((r >> 1) & 3)) * 8);
    }
    #pragma unroll
    for (int i = 0; i < ACW; ++i) {
        int cid = i * BS + tid;
        int r = cid >> 2, c = cid & 3;
        int rg = col0 + r; if (rg > N - 1) rg = N - 1;   // clamp: dup, store-guarded
        gW[i] = W + (size_t)rg * ldw + ((c ^ ((r >> 1) & 3)) * 8);
    }

    const int arow = wr * (MT / WRG) + (lane & 15);
    const int brow = wc * 64 + (lane & 15);
    const int szA = (arow >> 1) & 3;          // row+16 invariant
    const int szB = (brow >> 1) & 3;
    const int hi = lane >> 4;                 // 0..3 (= k-chunk for BKT=32)

    auto STAGE = [&](int buf) {
        short* As = smem + buf * BUFS;
        short* Ws = As + MT * BKT;
        #pragma unroll
        for (int i = 0; i < ACA; ++i) {
            int cbase = (ACH >= BS) ? (i * BS + wid * 64)
                                    : ((wid % (ACH / 64)) * 64);
            gl_lds16(gA[i], &As[cbase * 8]);
            gA[i] += BKT;
        }
        #pragma unroll
        for (int i = 0; i < ACW; ++i) {
            gl_lds16(gW[i], &Ws[(i * BS + wid * 64) * 8]);
            gW[i] += BKT;
        }
    };

    f32x4 acc[MFR][4] = {};

    const int ntiles = K / BKT;               // >= 24 at all call sites
    #pragma unroll
    for (int p = 0; p < PF; ++p) STAGE(p);

    for (int t = 0; t < ntiles; ++t) {
        if (t + PF < ntiles) STAGE((t + PF) % NBUF);   // deepest prefetch
        int ahead = ntiles - 1 - t;
        if (ahead > PF) ahead = PF;
        // counted waits: tile t landed, newer tiles stay in flight
        if (PF >= 2 && ahead == 2)
            asm volatile("s_waitcnt vmcnt(%0)" :: "n"(2 * ISS) : "memory");
        else if (ahead == 1)
            asm volatile("s_waitcnt vmcnt(%0)" :: "n"(ISS) : "memory");
        else if (ahead == 0)
            asm volatile("s_waitcnt vmcnt(0)" ::: "memory");
        __builtin_amdgcn_sched_barrier(0);
        __builtin_amdgcn_s_barrier();      // tile-t buffer visible to all waves

        const short* As = smem + (t % NBUF) * BUFS;
        const short* Ws = As + MT * BKT;
        bf16x8 a[MFR], b[4];
        #pragma unroll
        for (int mf = 0; mf < MFR; ++mf)
            a[mf] = *reinterpret_cast<const bf16x8*>(
                &As[(arow + mf * 16) * BKT + ((hi ^ szA) * 8)]);
        #pragma unroll
        for (int nf = 0; nf < 4; ++nf)
            b[nf] = *reinterpret_cast<const bf16x8*>(
                &Ws[(brow + nf * 16) * BKT + ((hi ^ szB) * 8)]);
        #pragma unroll
        for (int mf = 0; mf < MFR; ++mf)
            #pragma unroll
            for (int nf = 0; nf < 4; ++nf)
                acc[mf][nf] = __builtin_amdgcn_mfma_f32_16x16x32_bf16(
                    a[mf], b[nf], acc[mf][nf], 0, 0, 0);

        if (!SB) __builtin_amdgcn_s_barrier();   // WAR guard (dual-barrier)
        // SB=true: WAR protected by NBUF >= PF+2 + next iter's top barrier
    }

    if (OUT == 0 && NTST) {
        __syncthreads();
        // LDS-transposed epilogue: full-line NT dword stores.
        float* Cs = (float*)smem;    // [WRG*16][132] fp32
        #pragma unroll
        for (int mf = 0; mf < MFR; ++mf) {
            __syncthreads();
            #pragma unroll
            for (int nf = 0; nf < 4; ++nf) {
                #pragma unroll
                for (int j = 0; j < 4; ++j)
                    Cs[(wr * 16 + hi * 4 + j) * 132 + wc * 64 + nf * 16 + (lane & 15)]
                        = acc[mf][nf][j];
            }
            __syncthreads();
            #pragma unroll
            for (int rr = 0; rr < 32 / (BS / 64); ++rr) {
                int lrow = wid * (32 / (BS / 64)) + rr;   // 0..31
                int qq = lrow >> 4, rmr = lrow & 15;
                int grow = row0 + qq * (MT / WRG) + mf * 16 + rmr;
                #pragma unroll
                for (int hf = 0; hf < 2; ++hf) {
                    int cc = col0 + hf * 64 + lane;
                    if (cc < N)
                        __builtin_nontemporal_store(
                            Cs[lrow * 132 + hf * 64 + lane],
                            &C[(size_t)grow * ldc + cc]);
                }
            }
        }
    } else {
        #pragma unroll
        for (int mf = 0; mf < MFR; ++mf) {
            #pragma unroll
            for (int nf = 0; nf < 4; ++nf) {
                int r  = row0 + wr * (MT / WRG) + mf * 16 + hi * 4;
                int cc = col0 + wc * 64 + nf * 16 + (lane & 15);
                if (cc < N) {
                    f32x4 d = acc[mf][nf];
                    if (OUT == 3) {
                        if (cc < DI) {
                            float bv = bias[cc];
                            #pragma unroll
                            for (int j = 0; j < 4; ++j) {
                                float v = d[j] + bv;
                                v = (v > 20.f) ? v : log1pf(__expf(v));
                                Cbf[(size_t)(r + j) * ldc + cc] = (unsigned short)f2bf(v);
                            }
                        } else {
                            #pragma unroll
                            for (int j = 0; j < 4; ++j)
                                aux[(size_t)(r + j) * 32 + (cc - DI)] = d[j];
                        }
                    } else if (OUT == 2) {
                        #pragma unroll
                        for (int j = 0; j < 4; ++j)
                            Cbf[(size_t)(r + j) * ldc + cc] = (unsigned short)f2bf(d[j]);
                    } else {
                        #pragma unroll
                        for (int j = 0; j < 4; ++j)
                            C[(size_t)(r + j) * ldc + cc] = d[j];
                    }
                }
            }
        }
    }
}

// ---------------------------------------------------------------------------
// Depthwise causal conv(4) + bias + silu, vectorized: 8 channels/thread.
// ---------------------------------------------------------------------------
__global__ __launch_bounds__(256) void conv_silu_k(
    const unsigned short* __restrict__ xz, const float* __restrict__ cw,
    const float* __restrict__ cb, unsigned short* __restrict__ xinb)
{
    int i = blockIdx.x * 256 + threadIdx.x;   // over ROWS * DI/8
    if (i >= ROWS * (DI / 8)) return;
    int row = i / (DI / 8);
    int c = (i - row * (DI / 8)) * 8;
    int t = row & (SL - 1);
    int b = row >> 10;

    float4 wv[8];
    float accv[8];
    #pragma unroll
    for (int j = 0; j < 8; ++j) {
        wv[j] = *reinterpret_cast<const float4*>(&cw[(c + j) * DC]);
        accv[j] = cb[c + j];
    }
    const unsigned short* base = xz + ((size_t)(b * SL)) * (2 * DI) + c;
    #pragma unroll
    for (int k = 0; k < DC; ++k) {
        int tt = t + k - (DC - 1);
        if (tt >= 0) {
            bf16x8 v = *reinterpret_cast<const bf16x8*>(
                &base[(size_t)tt * (2 * DI)]);
            #pragma unroll
            for (int j = 0; j < 8; ++j)
                accv[j] += bf2f((unsigned short)v[j]) *
                           reinterpret_cast<const float*>(&wv[j])[k];
        }
    }
    bf16x8 o;
    #pragma unroll
    for (int j = 0; j < 8; ++j) {
        float v = accv[j] / (1.f + __expf(-accv[j]));
        o[j] = f2bf(v);
    }
    *reinterpret_cast<bf16x8*>(&xinb[(size_t)row * DI + c]) = o;
}

// ---------------------------------------------------------------------------
// Chunked selective scan, 2 kernels. CCH=32 chunks of CLEN=32.
// Batched loads: lane s loads step-s dt/xin/z once per 16-step batch (shfl
// broadcast); bc chunk staged in LDS (one float4 per thread, broadcast reads).
// ---------------------------------------------------------------------------
__global__ __launch_bounds__(256) void scan_phase1(
    const unsigned short* __restrict__ dt,
    const float* __restrict__ bc,
    const unsigned short* __restrict__ xin,
    const float* __restrict__ Alog,
    float* __restrict__ hend,
    float* __restrict__ eprod)
{
    int blk = blockIdx.x;
    int c = blk % CCH;
    int tmp = blk / CCH;
    int dblk = tmp % (DI / 16);
    int b = tmp / (DI / 16);
    int lane = threadIdx.x & 63;
    int s = lane & 15;
    int g = lane & 0x30;                 // d-group base within wave
    int d = dblk * 16 + (threadIdx.x >> 4);
    const int rowbase = b * SL + c * CLEN;

    __shared__ float sbc[CLEN * 32];     // 4 KB: B/C for the whole chunk
    *reinterpret_cast<float4*>(&sbc[threadIdx.x * 4]) =
        *reinterpret_cast<const float4*>(&bc[(size_t)rowbase * 32 + threadIdx.x * 4]);
    float A = -__expf(Alog[d * DS + s]);
    __syncthreads();

    float h = 0.f, P = 1.f;
    #pragma unroll
    for (int half = 0; half < 2; ++half) {
        int rb = rowbase + half * 16;
        int rl = rb + s;                 // loader row for this lane
        float dtv_b = bf2f(dt[(size_t)rl * DI + d]);
        float xv_b  = bf2f(xin[(size_t)rl * DI + d]);
        #pragma unroll
        for (int t = 0; t < 16; ++t) {
            float dtv = __shfl(dtv_b, g | t, 64);
            float xv  = __shfl(xv_b,  g | t, 64);
            float Bv  = sbc[(half * 16 + t) * 32 + s];
            float e = __expf(dtv * A);
            h = h * e + dtv * xv * Bv;
            P *= e;
        }
    }
    size_t idx = ((size_t)(b * CCH + c) * DI + d) * DS + s;
    hend[idx]  = h;
    eprod[idx] = P;
}

__global__ __launch_bounds__(256) void scan_phase3(
    const unsigned short* __restrict__ dt,
    const float* __restrict__ bc,
    const unsigned short* __restrict__ xin,
    const unsigned short* __restrict__ xz,   // z = cols [DI:2*DI)
    const float* __restrict__ Alog,
    const float* __restrict__ Dp,
    const float* __restrict__ hend,
    const float* __restrict__ eprod,
    unsigned short* __restrict__ ybf)
{
    int blk = blockIdx.x;
    int c = blk % CCH;
    int tmp = blk / CCH;
    int dblk = tmp % (DI / 16);
    int b = tmp / (DI / 16);
    int lane = threadIdx.x & 63;
    int s = lane & 15;
    int g = lane & 0x30;
    int d = dblk * 16 + (threadIdx.x >> 4);
    const int rowbase = b * SL + c * CLEN;

    __shared__ float sbc[CLEN * 32];
    *reinterpret_cast<float4*>(&sbc[threadIdx.x * 4]) =
        *reinterpret_cast<const float4*>(&bc[(size_t)rowbase * 32 + threadIdx.x * 4]);
    float A = -__expf(Alog[d * DS + s]);
    float Dv = Dp[d];

    float h = 0.f;
    const size_t pbase = ((size_t)b * CCH * DI + d) * DS + s;
    for (int j = 0; j < c; ++j) {
        size_t idx = pbase + (size_t)j * (DI * DS);
        h = h * eprod[idx] + hend[idx];
    }
    __syncthreads();

    #pragma unroll
    for (int half = 0; half < 2; ++half) {
        int rb = rowbase + half * 16;
        int rl = rb + s;
        float dtv_b = bf2f(dt[(size_t)rl * DI + d]);
        float xv_b  = bf2f(xin[(size_t)rl * DI + d]);
        float zv_b  = bf2f(xz[(size_t)rl * (2 * DI) + DI + d]);
        #pragma unroll
        for (int t = 0; t < 16; ++t) {
            float dtv = __shfl(dtv_b, g | t, 64);
            float xv  = __shfl(xv_b,  g | t, 64);
            int r = rb + t;
            float Bv  = sbc[(half * 16 + t) * 32 + s];
            float Cv  = sbc[(half * 16 + t) * 32 + 16 + s];
            float e = __expf(dtv * A);
            h = h * e + dtv * xv * Bv;
            float p = h * Cv;
            p += __shfl_xor(p, 1, 64);
            p += __shfl_xor(p, 2, 64);
            p += __shfl_xor(p, 4, 64);
            p += __shfl_xor(p, 8, 64);
            float z = __shfl(zv_b, g | t, 64);
            if (s == 0) {
                float yv = (p + xv * Dv) * (z / (1.f + __expf(-z)));
                ybf[(size_t)r * DI + d] = (unsigned short)f2bf(yv);
            }
        }
    }
}

// ---------------------------------------------------------------------------
// LayerNorm over rows of 768, bf16 in, bf16 out
// ---------------------------------------------------------------------------
__global__ __launch_bounds__(256) void ln_k(
    const unsigned short* __restrict__ x, const float* __restrict__ w,
    const float* __restrict__ b, unsigned short* __restrict__ o)
{
    int row = blockIdx.x;
    int tid = threadIdx.x;
    const unsigned short* xr = x + (size_t)row * DM;
    float v0 = bf2f(xr[tid]), v1 = bf2f(xr[tid + 256]), v2 = bf2f(xr[tid + 512]);
    float s = v0 + v1 + v2;
    #pragma unroll
    for (int off = 1; off < 64; off <<= 1) s += __shfl_xor(s, off, 64);
    __shared__ float red[4];
    __shared__ float red2[4];
    int wid = tid >> 6, lane = tid & 63;
    if (lane == 0) red[wid] = s;
    __syncthreads();
    float mu = (red[0] + red[1] + red[2] + red[3]) * (1.f / 768.f);
    float d0 = v0 - mu, d1 = v1 - mu, d2 = v2 - mu;
    float q = d0 * d0 + d1 * d1 + d2 * d2;
    #pragma unroll
    for (int off = 1; off < 64; off <<= 1) q += __shfl_xor(q, off, 64);
    if (lane == 0) red2[wid] = q;
    __syncthreads();
    float var = (red2[0] + red2[1] + red2[2] + red2[3]) * (1.f / 768.f);
    float rs = rsqrtf(var + 1e-5f);
    o[(size_t)row * DM + tid]       = (unsigned short)f2bf(d0 * rs * w[tid]       + b[tid]);
    o[(size_t)row * DM + tid + 256] = (unsigned short)f2bf(d1 * rs * w[tid + 256] + b[tid + 256]);
    o[(size_t)row * DM + tid + 512] = (unsigned short)f2bf(d2 * rs * w[tid + 512] + b[tid + 512]);
}

// ---------------------------------------------------------------------------
extern "C" void kernel_launch(void* const* d_in, const int* in_sizes, int n_in,
                              void* d_out, int out_size, void* d_ws, size_t ws_size,
                              hipStream_t stream) {
    const int*   ids        = (const int*)d_in[0];
    const float* emb        = (const float*)d_in[1];
    const float* in_proj_w  = (const float*)d_in[2];
    const float* conv_w     = (const float*)d_in[3];
    const float* conv_b     = (const float*)d_in[4];
    const float* x_proj_w   = (const float*)d_in[5];
    const float* dt_proj_w  = (const float*)d_in[6];
    const float* dt_proj_b  = (const float*)d_in[7];
    const float* A_log      = (const float*)d_in[8];
    const float* D_param    = (const float*)d_in[9];
    const float* out_proj_w = (const float*)d_in[10];
    const float* norm_w     = (const float*)d_in[11];
    const float* norm_b     = (const float*)d_in[12];
    float* out = (float*)d_out;

    // ---- workspace layout ----
    char* base = (char*)d_ws;
    size_t off = 0;
    auto alloc_f = [&](size_t n) { float* p = (float*)(base + off); off += n * 4; return p; };
    auto alloc_u = [&](size_t n) { unsigned short* p = (unsigned short*)(base + off); off += n * 2; return p; };

    float* bc    = alloc_f((size_t)ROWS * 32);
    float* hend  = alloc_f((size_t)NB * CCH * DI * DS);
    float* eprod = alloc_f((size_t)NB * CCH * DI * DS);
    unsigned short* xbf   = alloc_u((size_t)ROWS * DM);
    unsigned short* xzb   = alloc_u((size_t)ROWS * 2 * DI);
    unsigned short* xinb  = alloc_u((size_t)ROWS * DI);
    unsigned short* dtbf  = alloc_u((size_t)ROWS * DI);
    unsigned short* ybf   = alloc_u((size_t)ROWS * DI);
    unsigned short* xlnbf = alloc_u((size_t)ROWS * DM);
    unsigned short* inw_bf = alloc_u((size_t)NLAYER * 2 * DI * DM);
    unsigned short* ow_bf  = alloc_u((size_t)NLAYER * DM * DI);
    unsigned short* wbig  = alloc_u((size_t)NLAYER * NBIG * DI);
    unsigned short* emb_bf = alloc_u((size_t)VOCAB * DM);
    (void)ws_size;

    // ---- weight preconversion (once per call, single cvt dispatch) ----
    {
        int n4a = NLAYER * 2 * DI * DM / 4;
        int n4b = NLAYER * DM * DI / 4;
        int n4e = VOCAB * DM / 4;
        int n4t = n4a + n4b + n4e;
        cvt3_k<<<(n4t + 255) / 256, 256, 0, stream>>>(
            in_proj_w, inw_bf, n4a, out_proj_w, ow_bf, n4b, emb, emb_bf, n4e);
        wc_k<<<dim3(12, 13, NLAYER), 256, 0, stream>>>(dt_proj_w, x_proj_w, wbig);
    }

    embed_k<<<(ROWS * (DM / 4) + 255) / 256, 256, 0, stream>>>(ids, emb, xbf);

    const int scan_grid = NB * (DI / 16) * CCH;      // 6144 blocks

    for (int i = 0; i < NLAYER; ++i) {
        const float* cw  = conv_w  + (size_t)i * DI * DC;
        const float* cb  = conv_b  + (size_t)i * DI;
        const float* dtb = dt_proj_b + (size_t)i * DI;
        const float* Al  = A_log   + (size_t)i * DI * DS;
        const float* Dpar= D_param + (size_t)i * DI;

        // in_proj: xzb(bf16) = xbf @ inw^T  (64-tile, single-barrier NBUF4/PF2)
        const unsigned short* inw = inw_bf + (size_t)i * 2 * DI * DM;
        gemm_bf16<256, 64, 4, 2, true, 2, false><<<24 * 32, 256, 0, stream>>>(
            xbf, DM, inw, DM, nullptr, xzb, 2 * DI, 32, 2 * DI, DM, nullptr, nullptr);

        conv_silu_k<<<(ROWS * (DI / 8)) / 256, 256, 0, stream>>>(xzb, cw, cb, xinb);

        // fused dt(bf16,softplus) + B/C(fp32): xinb @ wbig[i]^T
        // (32-row tile -> 832 blocks = 3.25/CU, removes grid tail)
        const unsigned short* wb = wbig + (size_t)i * NBIG * DI;
        gemm_bf16<256, 32, 4, 2, true, 3, false><<<13 * 64, 256, 0, stream>>>(
            xinb, DI, wb, DI, nullptr, dtbf, DI, 64, NBIG, DI, dtb, bc);

        scan_phase1<<<scan_grid, 256, 0, stream>>>(dtbf, bc, xinb, Al, hend, eprod);
        scan_phase3<<<scan_grid, 256, 0, stream>>>(dtbf, bc, xinb, xzb, Al, Dpar,
                                                   hend, eprod, ybf);

        // out_proj: xbf(bf16) = ybf @ ow^T  (32-tile, single-barrier NBUF4/PF2)
        const unsigned short* ow = ow_bf + (size_t)i * DM * DI;
        gemm_bf16<256, 32, 4, 2, true, 2, false><<<64 * 6, 256, 0, stream>>>(
            ybf, DI, ow, DI, nullptr, xbf, DM, 64, DM, DI, nullptr, nullptr);
    }

    ln_k<<<ROWS, 256, 0, stream>>>(xbf, norm_w, norm_b, xlnbf);
    // logits: out = xlnbf @ emb^T  (empirical optimum of this family:
    // 128-tile, dual-barrier NBUF2/PF1, NT transposed epilogue; 255 us)
    gemm_bf16<256, 128, 2, 1, false, 0, true><<<393 * 16, 256, 0, stream>>>(
        xlnbf, DM, emb_bf, DM, out, nullptr, VOCAB, 16, VOCAB, DM, nullptr, nullptr);
}

// Round 19
// 2747.618 us; speedup vs baseline: 1.0408x; 1.0408x over previous
//
#include <hip/hip_runtime.h>
#include <hip/hip_bf16.h>

#define DI 1536
#define DS 16
#define DC 4
#define DTR 48
#define NB 2
#define SL 1024
#define DM 768
#define NLAYER 12
#define VOCAB 50257
#define ROWS (NB*SL)   // 2048
#define CCH 32         // scan chunks
#define CLEN (SL/CCH)  // 32
#define NBIG (DI+32)   // 1568: fused dt(1536) + B/C(32) outputs

typedef __attribute__((ext_vector_type(8))) short bf16x8;
typedef __attribute__((ext_vector_type(4))) short short4v;
typedef __attribute__((ext_vector_type(4))) float f32x4;

__device__ inline short f2bf(float f) {
    unsigned u = __builtin_bit_cast(unsigned, f);
    unsigned r = (u + 0x7fffu + ((u >> 16) & 1u)) >> 16;
    return (short)r;
}
__device__ inline float bf2f(unsigned short u) {
    unsigned x = ((unsigned)u) << 16;
    return __builtin_bit_cast(float, x);
}

__device__ __forceinline__ void gl_lds16(const void* g, void* l) {
    __builtin_amdgcn_global_load_lds(
        (const __attribute__((address_space(1))) unsigned int*)g,
        (__attribute__((address_space(3))) unsigned int*)l, 16, 0, 0);
}

// ---------------------------------------------------------------------------
// fp32 -> bf16 convert for 3 arrays in one dispatch (each n multiple of 4)
// ---------------------------------------------------------------------------
__global__ __launch_bounds__(256) void cvt3_k(
    const float* __restrict__ s0, unsigned short* __restrict__ d0, int n40,
    const float* __restrict__ s1, unsigned short* __restrict__ d1, int n41,
    const float* __restrict__ s2, unsigned short* __restrict__ d2, int n42)
{
    int i = blockIdx.x * 256 + threadIdx.x;
    const float* src; unsigned short* dst;
    if (i < n40) { src = s0; dst = d0; }
    else if (i < n40 + n41) { i -= n40; src = s1; dst = d1; }
    else if (i < n40 + n41 + n42) { i -= n40 + n41; src = s2; dst = d2; }
    else return;
    float4 v = *reinterpret_cast<const float4*>(src + (size_t)i * 4);
    short4v o;
    o[0] = f2bf(v.x); o[1] = f2bf(v.y); o[2] = f2bf(v.z); o[3] = f2bf(v.w);
    *reinterpret_cast<short4v*>(dst + (size_t)i * 4) = o;
}

// ---------------------------------------------------------------------------
// Wc precompute: wbig[l] rows 0..1535 = dtw @ xpw[:48]  (bf16),
//                rows 1536..1567 = xpw[48:80] (bf16).
// ---------------------------------------------------------------------------
__global__ __launch_bounds__(256) void wc_k(
    const float* __restrict__ dtw_all,   // (NL, DI, DTR)
    const float* __restrict__ xpw_all,   // (NL, 80, DI)
    unsigned short* __restrict__ wbig)   // (NL, NBIG, DI)
{
    int l = blockIdx.z;
    const float* dtw = dtw_all + (size_t)l * DI * DTR;
    const float* xpw = xpw_all + (size_t)l * 80 * DI;
    unsigned short* wb = wbig + (size_t)l * NBIG * DI;
    int tid = threadIdx.x;
    if (blockIdx.y == 12) {
        if (blockIdx.x == 0) {
            for (int idx = tid; idx < 32 * DI; idx += 256) {
                int rr = idx / DI, k = idx - rr * DI;
                wb[(size_t)(DI + rr) * DI + k] =
                    (unsigned short)f2bf(xpw[(size_t)(48 + rr) * DI + k]);
            }
        }
        return;
    }
    __shared__ float sd[128 * 48];
    __shared__ float sx[48 * 128];
    int d0 = blockIdx.y * 128, k0 = blockIdx.x * 128;
    for (int idx = tid; idx < 128 * 48; idx += 256) {
        int r = idx / 48, j = idx - r * 48;
        sd[idx] = dtw[(size_t)(d0 + r) * DTR + j];
    }
    for (int idx = tid; idx < 48 * 128; idx += 256) {
        int j = idx / 128, k = idx - j * 128;
        sx[idx] = xpw[(size_t)j * DI + k0 + k];
    }
    __syncthreads();
    int tx = tid & 15, ty = tid >> 4;
    float acc[8][8] = {};
    for (int j = 0; j < 48; ++j) {
        float a[8], w[8];
        #pragma unroll
        for (int i = 0; i < 8; ++i) a[i] = sd[(ty * 8 + i) * 48 + j];
        #pragma unroll
        for (int i = 0; i < 8; ++i) w[i] = sx[j * 128 + tx * 8 + i];
        #pragma unroll
        for (int i = 0; i < 8; ++i)
            #pragma unroll
            for (int jj = 0; jj < 8; ++jj)
                acc[i][jj] += a[i] * w[jj];
    }
    for (int i = 0; i < 8; ++i)
        for (int jj = 0; jj < 8; ++jj)
            wb[(size_t)(d0 + ty * 8 + i) * DI + k0 + tx * 8 + jj] =
                (unsigned short)f2bf(acc[i][jj]);
}

// ---------------------------------------------------------------------------
// Embedding (vectorized x4)
// ---------------------------------------------------------------------------
__global__ __launch_bounds__(256) void embed_k(const int* __restrict__ ids,
                                               const float* __restrict__ emb,
                                               unsigned short* __restrict__ xbf) {
    int i = blockIdx.x * 256 + threadIdx.x;      // over ROWS * DM/4
    if (i >= ROWS * (DM / 4)) return;
    int row = i / (DM / 4);
    int c4 = (i - row * (DM / 4)) * 4;
    float4 v = *reinterpret_cast<const float4*>(
        &emb[(size_t)ids[row] * DM + c4]);
    const float s = 27.712812921102035f;
    short4v o;
    o[0] = f2bf(v.x * s); o[1] = f2bf(v.y * s);
    o[2] = f2bf(v.z * s); o[3] = f2bf(v.w * s);
    *reinterpret_cast<short4v*>(&xbf[(size_t)row * DM + c4]) = o;
}

// ---------------------------------------------------------------------------
// bf16-MFMA GEMM with COUNTED vmcnt (T3/T4). Two schedule variants:
//   SB=false (dual-barrier): NBUF >= PF+1. Trailing s_barrier WAR-guards the
//            slot re-staged next iter. (Logits optimum: MT128/NBUF2/PF1.)
//   SB=true  (single-barrier): NBUF >= PF+2 so the slot staged at iter t was
//            last read at iter t-2; the iter t-1 top barrier orders it.
//            (Layer GEMMs: NBUF4/PF2.)
// BS=256 threads (4 waves 2x2), MT x 128 tile, BKT=32.
// global_load_lds staging, linear LDS dest, pre-swizzled source
// (involution chunk ^ ((row>>1)&3), conflict-free ds_read_b128).
// OUT: 0 = fp32 store (NTST -> LDS-transposed full-line NT epilogue);
//      2 = bf16-only store; 3 = fused dt softplus (bf16) / BC (fp32) split.
// ---------------------------------------------------------------------------
template<int BS, int MT, int NBUF, int PF, bool SB, int OUT, bool NTST>
__global__ __launch_bounds__(BS) void gemm_bf16(
    const unsigned short* __restrict__ A, int lda,
    const unsigned short* __restrict__ W, int ldw,
    float* __restrict__ C, unsigned short* __restrict__ Cbf, int ldc,
    int GY, int N, int K,
    const float* __restrict__ bias, float* __restrict__ aux)
{
    static_assert(SB ? (NBUF >= PF + 2) : (NBUF >= PF + 1),
                  "WAR safety: SB needs NBUF>=PF+2, dual-barrier NBUF>=PF+1");
    constexpr int BKT = 32;
    constexpr int WRG = (BS / 64) / 2;            // wr groups (2)
    constexpr int ACH = MT * (BKT / 8);           // A chunks per tile
    constexpr int ACA = (ACH >= BS) ? ACH / BS : 1;
    constexpr int ACW = (128 * (BKT / 8)) / BS;   // W staging issues/thread
    constexpr int ISS = ACA + ACW;                // gl_lds instrs per STAGE
    constexpr int MFR = MT / (16 * WRG);          // M fragments per wave
    constexpr int BUFS = (MT + 128) * BKT;        // shorts per buffer
    __shared__ __align__(16) short smem[NBUF * BUFS];

    const int tid  = threadIdx.x;
    const int lane = tid & 63;
    const int wid  = tid >> 6;
    const int wr   = wid >> 1, wc = wid & 1;

    // bijective XCD-chunked swizzle, then col-major decode
    const int nwg = gridDim.x;
    const int q = nwg >> 3, rm = nwg & 7;
    const int xcd = blockIdx.x & 7, bidx = blockIdx.x >> 3;
    const int wg = (xcd < rm ? xcd * (q + 1) : rm * (q + 1) + (xcd - rm) * q) + bidx;
    const int row0 = (wg % GY) * MT;
    const int col0 = (wg / GY) * 128;

    // ---- staging setup (pre-swizzled global sources) ----
    const unsigned short* gA[ACA];
    const unsigned short* gW[ACW];
    #pragma unroll
    for (int i = 0; i < ACA; ++i) {
        int cid = (ACH >= BS) ? (i * BS + tid) : (tid & (ACH - 1));
        int r = cid >> 2, c = cid & 3;
        gA[i] = A + (size_t)(row0 + r) * lda + ((c ^ ((r >> 1) & 3)) * 8);
    }
    #pragma unroll
    for (int i = 0; i < ACW; ++i) {
        int cid = i * BS + tid;
        int r = cid >> 2, c = cid & 3;
        int rg = col0 + r; if (rg > N - 1) rg = N - 1;   // clamp: dup, store-guarded
        gW[i] = W + (size_t)rg * ldw + ((c ^ ((r >> 1) & 3)) * 8);
    }

    const int arow = wr * (MT / WRG) + (lane & 15);
    const int brow = wc * 64 + (lane & 15);
    const int szA = (arow >> 1) & 3;          // row+16 invariant
    const int szB = (brow >> 1) & 3;
    const int hi = lane >> 4;                 // 0..3 (= k-chunk for BKT=32)

    auto STAGE = [&](int buf) {
        short* As = smem + buf * BUFS;
        short* Ws = As + MT * BKT;
        #pragma unroll
        for (int i = 0; i < ACA; ++i) {
            int cbase = (ACH >= BS) ? (i * BS + wid * 64)
                                    : ((wid % (ACH / 64)) * 64);
            gl_lds16(gA[i], &As[cbase * 8]);
            gA[i] += BKT;
        }
        #pragma unroll
        for (int i = 0; i < ACW; ++i) {
            gl_lds16(gW[i], &Ws[(i * BS + wid * 64) * 8]);
            gW[i] += BKT;
        }
    };

    f32x4 acc[MFR][4] = {};

    const int ntiles = K / BKT;               // >= 24 at all call sites
    #pragma unroll
    for (int p = 0; p < PF; ++p) STAGE(p);

    for (int t = 0; t < ntiles; ++t) {
        if (t + PF < ntiles) STAGE((t + PF) % NBUF);   // deepest prefetch
        int ahead = ntiles - 1 - t;
        if (ahead > PF) ahead = PF;
        // counted waits: tile t landed, newer tiles stay in flight
        if (PF >= 2 && ahead == 2)
            asm volatile("s_waitcnt vmcnt(%0)" :: "n"(2 * ISS) : "memory");
        else if (ahead == 1)
            asm volatile("s_waitcnt vmcnt(%0)" :: "n"(ISS) : "memory");
        else if (ahead == 0)
            asm volatile("s_waitcnt vmcnt(0)" ::: "memory");
        __builtin_amdgcn_sched_barrier(0);
        __builtin_amdgcn_s_barrier();      // tile-t buffer visible to all waves

        const short* As = smem + (t % NBUF) * BUFS;
        const short* Ws = As + MT * BKT;
        bf16x8 a[MFR], b[4];
        #pragma unroll
        for (int mf = 0; mf < MFR; ++mf)
            a[mf] = *reinterpret_cast<const bf16x8*>(
                &As[(arow + mf * 16) * BKT + ((hi ^ szA) * 8)]);
        #pragma unroll
        for (int nf = 0; nf < 4; ++nf)
            b[nf] = *reinterpret_cast<const bf16x8*>(
                &Ws[(brow + nf * 16) * BKT + ((hi ^ szB) * 8)]);
        #pragma unroll
        for (int mf = 0; mf < MFR; ++mf)
            #pragma unroll
            for (int nf = 0; nf < 4; ++nf)
                acc[mf][nf] = __builtin_amdgcn_mfma_f32_16x16x32_bf16(
                    a[mf], b[nf], acc[mf][nf], 0, 0, 0);

        if (!SB) __builtin_amdgcn_s_barrier();   // WAR guard (dual-barrier)
        // SB=true: WAR protected by NBUF >= PF+2 + next iter's top barrier
    }

    if (OUT == 0 && NTST) {
        __syncthreads();
        // LDS-transposed epilogue: full-line NT dword stores.
        float* Cs = (float*)smem;    // [WRG*16][132] fp32
        #pragma unroll
        for (int mf = 0; mf < MFR; ++mf) {
            __syncthreads();
            #pragma unroll
            for (int nf = 0; nf < 4; ++nf) {
                #pragma unroll
                for (int j = 0; j < 4; ++j)
                    Cs[(wr * 16 + hi * 4 + j) * 132 + wc * 64 + nf * 16 + (lane & 15)]
                        = acc[mf][nf][j];
            }
            __syncthreads();
            #pragma unroll
            for (int rr = 0; rr < 32 / (BS / 64); ++rr) {
                int lrow = wid * (32 / (BS / 64)) + rr;   // 0..31
                int qq = lrow >> 4, rmr = lrow & 15;
                int grow = row0 + qq * (MT / WRG) + mf * 16 + rmr;
                #pragma unroll
                for (int hf = 0; hf < 2; ++hf) {
                    int cc = col0 + hf * 64 + lane;
                    if (cc < N)
                        __builtin_nontemporal_store(
                            Cs[lrow * 132 + hf * 64 + lane],
                            &C[(size_t)grow * ldc + cc]);
                }
            }
        }
    } else {
        #pragma unroll
        for (int mf = 0; mf < MFR; ++mf) {
            #pragma unroll
            for (int nf = 0; nf < 4; ++nf) {
                int r  = row0 + wr * (MT / WRG) + mf * 16 + hi * 4;
                int cc = col0 + wc * 64 + nf * 16 + (lane & 15);
                if (cc < N) {
                    f32x4 d = acc[mf][nf];
                    if (OUT == 3) {
                        if (cc < DI) {
                            float bv = bias[cc];
                            #pragma unroll
                            for (int j = 0; j < 4; ++j) {
                                float v = d[j] + bv;
                                v = (v > 20.f) ? v : log1pf(__expf(v));
                                Cbf[(size_t)(r + j) * ldc + cc] = (unsigned short)f2bf(v);
                            }
                        } else {
                            #pragma unroll
                            for (int j = 0; j < 4; ++j)
                                aux[(size_t)(r + j) * 32 + (cc - DI)] = d[j];
                        }
                    } else if (OUT == 2) {
                        #pragma unroll
                        for (int j = 0; j < 4; ++j)
                            Cbf[(size_t)(r + j) * ldc + cc] = (unsigned short)f2bf(d[j]);
                    } else {
                        #pragma unroll
                        for (int j = 0; j < 4; ++j)
                            C[(size_t)(r + j) * ldc + cc] = d[j];
                    }
                }
            }
        }
    }
}

// ---------------------------------------------------------------------------
// Depthwise causal conv(4) + bias + silu, vectorized: 8 channels/thread.
// ---------------------------------------------------------------------------
__global__ __launch_bounds__(256) void conv_silu_k(
    const unsigned short* __restrict__ xz, const float* __restrict__ cw,
    const float* __restrict__ cb, unsigned short* __restrict__ xinb)
{
    int i = blockIdx.x * 256 + threadIdx.x;   // over ROWS * DI/8
    if (i >= ROWS * (DI / 8)) return;
    int row = i / (DI / 8);
    int c = (i - row * (DI / 8)) * 8;
    int t = row & (SL - 1);
    int b = row >> 10;

    float4 wv[8];
    float accv[8];
    #pragma unroll
    for (int j = 0; j < 8; ++j) {
        wv[j] = *reinterpret_cast<const float4*>(&cw[(c + j) * DC]);
        accv[j] = cb[c + j];
    }
    const unsigned short* base = xz + ((size_t)(b * SL)) * (2 * DI) + c;
    #pragma unroll
    for (int k = 0; k < DC; ++k) {
        int tt = t + k - (DC - 1);
        if (tt >= 0) {
            bf16x8 v = *reinterpret_cast<const bf16x8*>(
                &base[(size_t)tt * (2 * DI)]);
            #pragma unroll
            for (int j = 0; j < 8; ++j)
                accv[j] += bf2f((unsigned short)v[j]) *
                           reinterpret_cast<const float*>(&wv[j])[k];
        }
    }
    bf16x8 o;
    #pragma unroll
    for (int j = 0; j < 8; ++j) {
        float v = accv[j] / (1.f + __expf(-accv[j]));
        o[j] = f2bf(v);
    }
    *reinterpret_cast<bf16x8*>(&xinb[(size_t)row * DI + c]) = o;
}

// ---------------------------------------------------------------------------
// Chunked selective scan, 2 kernels. CCH=32 chunks of CLEN=32.
// Batched loads: lane s loads step-s dt/xin/z once per 16-step batch (shfl
// broadcast); bc chunk staged in LDS (one float4 per thread, broadcast reads).
// ---------------------------------------------------------------------------
__global__ __launch_bounds__(256) void scan_phase1(
    const unsigned short* __restrict__ dt,
    const float* __restrict__ bc,
    const unsigned short* __restrict__ xin,
    const float* __restrict__ Alog,
    float* __restrict__ hend,
    float* __restrict__ eprod)
{
    int blk = blockIdx.x;
    int c = blk % CCH;
    int tmp = blk / CCH;
    int dblk = tmp % (DI / 16);
    int b = tmp / (DI / 16);
    int lane = threadIdx.x & 63;
    int s = lane & 15;
    int g = lane & 0x30;                 // d-group base within wave
    int d = dblk * 16 + (threadIdx.x >> 4);
    const int rowbase = b * SL + c * CLEN;

    __shared__ float sbc[CLEN * 32];     // 4 KB: B/C for the whole chunk
    *reinterpret_cast<float4*>(&sbc[threadIdx.x * 4]) =
        *reinterpret_cast<const float4*>(&bc[(size_t)rowbase * 32 + threadIdx.x * 4]);
    float A = -__expf(Alog[d * DS + s]);
    __syncthreads();

    float h = 0.f, P = 1.f;
    #pragma unroll
    for (int half = 0; half < 2; ++half) {
        int rb = rowbase + half * 16;
        int rl = rb + s;                 // loader row for this lane
        float dtv_b = bf2f(dt[(size_t)rl * DI + d]);
        float xv_b  = bf2f(xin[(size_t)rl * DI + d]);
        #pragma unroll
        for (int t = 0; t < 16; ++t) {
            float dtv = __shfl(dtv_b, g | t, 64);
            float xv  = __shfl(xv_b,  g | t, 64);
            float Bv  = sbc[(half * 16 + t) * 32 + s];
            float e = __expf(dtv * A);
            h = h * e + dtv * xv * Bv;
            P *= e;
        }
    }
    size_t idx = ((size_t)(b * CCH + c) * DI + d) * DS + s;
    hend[idx]  = h;
    eprod[idx] = P;
}

__global__ __launch_bounds__(256) void scan_phase3(
    const unsigned short* __restrict__ dt,
    const float* __restrict__ bc,
    const unsigned short* __restrict__ xin,
    const unsigned short* __restrict__ xz,   // z = cols [DI:2*DI)
    const float* __restrict__ Alog,
    const float* __restrict__ Dp,
    const float* __restrict__ hend,
    const float* __restrict__ eprod,
    unsigned short* __restrict__ ybf)
{
    int blk = blockIdx.x;
    int c = blk % CCH;
    int tmp = blk / CCH;
    int dblk = tmp % (DI / 16);
    int b = tmp / (DI / 16);
    int lane = threadIdx.x & 63;
    int s = lane & 15;
    int g = lane & 0x30;
    int d = dblk * 16 + (threadIdx.x >> 4);
    const int rowbase = b * SL + c * CLEN;

    __shared__ float sbc[CLEN * 32];
    *reinterpret_cast<float4*>(&sbc[threadIdx.x * 4]) =
        *reinterpret_cast<const float4*>(&bc[(size_t)rowbase * 32 + threadIdx.x * 4]);
    float A = -__expf(Alog[d * DS + s]);
    float Dv = Dp[d];

    float h = 0.f;
    const size_t pbase = ((size_t)b * CCH * DI + d) * DS + s;
    for (int j = 0; j < c; ++j) {
        size_t idx = pbase + (size_t)j * (DI * DS);
        h = h * eprod[idx] + hend[idx];
    }
    __syncthreads();

    #pragma unroll
    for (int half = 0; half < 2; ++half) {
        int rb = rowbase + half * 16;
        int rl = rb + s;
        float dtv_b = bf2f(dt[(size_t)rl * DI + d]);
        float xv_b  = bf2f(xin[(size_t)rl * DI + d]);
        float zv_b  = bf2f(xz[(size_t)rl * (2 * DI) + DI + d]);
        #pragma unroll
        for (int t = 0; t < 16; ++t) {
            float dtv = __shfl(dtv_b, g | t, 64);
            float xv  = __shfl(xv_b,  g | t, 64);
            int r = rb + t;
            float Bv  = sbc[(half * 16 + t) * 32 + s];
            float Cv  = sbc[(half * 16 + t) * 32 + 16 + s];
            float e = __expf(dtv * A);
            h = h * e + dtv * xv * Bv;
            float p = h * Cv;
            p += __shfl_xor(p, 1, 64);
            p += __shfl_xor(p, 2, 64);
            p += __shfl_xor(p, 4, 64);
            p += __shfl_xor(p, 8, 64);
            float z = __shfl(zv_b, g | t, 64);
            if (s == 0) {
                float yv = (p + xv * Dv) * (z / (1.f + __expf(-z)));
                ybf[(size_t)r * DI + d] = (unsigned short)f2bf(yv);
            }
        }
    }
}

// ---------------------------------------------------------------------------
// LayerNorm over rows of 768, bf16 in, bf16 out
// ---------------------------------------------------------------------------
__global__ __launch_bounds__(256) void ln_k(
    const unsigned short* __restrict__ x, const float* __restrict__ w,
    const float* __restrict__ b, unsigned short* __restrict__ o)
{
    int row = blockIdx.x;
    int tid = threadIdx.x;
    const unsigned short* xr = x + (size_t)row * DM;
    float v0 = bf2f(xr[tid]), v1 = bf2f(xr[tid + 256]), v2 = bf2f(xr[tid + 512]);
    float s = v0 + v1 + v2;
    #pragma unroll
    for (int off = 1; off < 64; off <<= 1) s += __shfl_xor(s, off, 64);
    __shared__ float red[4];
    __shared__ float red2[4];
    int wid = tid >> 6, lane = tid & 63;
    if (lane == 0) red[wid] = s;
    __syncthreads();
    float mu = (red[0] + red[1] + red[2] + red[3]) * (1.f / 768.f);
    float d0 = v0 - mu, d1 = v1 - mu, d2 = v2 - mu;
    float q = d0 * d0 + d1 * d1 + d2 * d2;
    #pragma unroll
    for (int off = 1; off < 64; off <<= 1) q += __shfl_xor(q, off, 64);
    if (lane == 0) red2[wid] = q;
    __syncthreads();
    float var = (red2[0] + red2[1] + red2[2] + red2[3]) * (1.f / 768.f);
    float rs = rsqrtf(var + 1e-5f);
    o[(size_t)row * DM + tid]       = (unsigned short)f2bf(d0 * rs * w[tid]       + b[tid]);
    o[(size_t)row * DM + tid + 256] = (unsigned short)f2bf(d1 * rs * w[tid + 256] + b[tid + 256]);
    o[(size_t)row * DM + tid + 512] = (unsigned short)f2bf(d2 * rs * w[tid + 512] + b[tid + 512]);
}

// ---------------------------------------------------------------------------
extern "C" void kernel_launch(void* const* d_in, const int* in_sizes, int n_in,
                              void* d_out, int out_size, void* d_ws, size_t ws_size,
                              hipStream_t stream) {
    const int*   ids        = (const int*)d_in[0];
    const float* emb        = (const float*)d_in[1];
    const float* in_proj_w  = (const float*)d_in[2];
    const float* conv_w     = (const float*)d_in[3];
    const float* conv_b     = (const float*)d_in[4];
    const float* x_proj_w   = (const float*)d_in[5];
    const float* dt_proj_w  = (const float*)d_in[6];
    const float* dt_proj_b  = (const float*)d_in[7];
    const float* A_log      = (const float*)d_in[8];
    const float* D_param    = (const float*)d_in[9];
    const float* out_proj_w = (const float*)d_in[10];
    const float* norm_w     = (const float*)d_in[11];
    const float* norm_b     = (const float*)d_in[12];
    float* out = (float*)d_out;

    // ---- workspace layout ----
    char* base = (char*)d_ws;
    size_t off = 0;
    auto alloc_f = [&](size_t n) { float* p = (float*)(base + off); off += n * 4; return p; };
    auto alloc_u = [&](size_t n) { unsigned short* p = (unsigned short*)(base + off); off += n * 2; return p; };

    float* bc    = alloc_f((size_t)ROWS * 32);
    float* hend  = alloc_f((size_t)NB * CCH * DI * DS);
    float* eprod = alloc_f((size_t)NB * CCH * DI * DS);
    unsigned short* xbf   = alloc_u((size_t)ROWS * DM);
    unsigned short* xzb   = alloc_u((size_t)ROWS * 2 * DI);
    unsigned short* xinb  = alloc_u((size_t)ROWS * DI);
    unsigned short* dtbf  = alloc_u((size_t)ROWS * DI);
    unsigned short* ybf   = alloc_u((size_t)ROWS * DI);
    unsigned short* xlnbf = alloc_u((size_t)ROWS * DM);
    unsigned short* inw_bf = alloc_u((size_t)NLAYER * 2 * DI * DM);
    unsigned short* ow_bf  = alloc_u((size_t)NLAYER * DM * DI);
    unsigned short* wbig  = alloc_u((size_t)NLAYER * NBIG * DI);
    unsigned short* emb_bf = alloc_u((size_t)VOCAB * DM);
    (void)ws_size;

    // ---- weight preconversion (once per call, single cvt dispatch) ----
    {
        int n4a = NLAYER * 2 * DI * DM / 4;
        int n4b = NLAYER * DM * DI / 4;
        int n4e = VOCAB * DM / 4;
        int n4t = n4a + n4b + n4e;
        cvt3_k<<<(n4t + 255) / 256, 256, 0, stream>>>(
            in_proj_w, inw_bf, n4a, out_proj_w, ow_bf, n4b, emb, emb_bf, n4e);
        wc_k<<<dim3(12, 13, NLAYER), 256, 0, stream>>>(dt_proj_w, x_proj_w, wbig);
    }

    embed_k<<<(ROWS * (DM / 4) + 255) / 256, 256, 0, stream>>>(ids, emb, xbf);

    const int scan_grid = NB * (DI / 16) * CCH;      // 6144 blocks

    for (int i = 0; i < NLAYER; ++i) {
        const float* cw  = conv_w  + (size_t)i * DI * DC;
        const float* cb  = conv_b  + (size_t)i * DI;
        const float* dtb = dt_proj_b + (size_t)i * DI;
        const float* Al  = A_log   + (size_t)i * DI * DS;
        const float* Dpar= D_param + (size_t)i * DI;

        // in_proj: xzb(bf16) = xbf @ inw^T  (64-tile, single-barrier NBUF4/PF2)
        const unsigned short* inw = inw_bf + (size_t)i * 2 * DI * DM;
        gemm_bf16<256, 64, 4, 2, true, 2, false><<<24 * 32, 256, 0, stream>>>(
            xbf, DM, inw, DM, nullptr, xzb, 2 * DI, 32, 2 * DI, DM, nullptr, nullptr);

        conv_silu_k<<<(ROWS * (DI / 8)) / 256, 256, 0, stream>>>(xzb, cw, cb, xinb);

        // fused dt(bf16,softplus) + B/C(fp32): xinb @ wbig[i]^T  (64-tile)
        const unsigned short* wb = wbig + (size_t)i * NBIG * DI;
        gemm_bf16<256, 64, 4, 2, true, 3, false><<<13 * 32, 256, 0, stream>>>(
            xinb, DI, wb, DI, nullptr, dtbf, DI, 32, NBIG, DI, dtb, bc);

        scan_phase1<<<scan_grid, 256, 0, stream>>>(dtbf, bc, xinb, Al, hend, eprod);
        scan_phase3<<<scan_grid, 256, 0, stream>>>(dtbf, bc, xinb, xzb, Al, Dpar,
                                                   hend, eprod, ybf);

        // out_proj: xbf(bf16) = ybf @ ow^T  (32-tile, single-barrier NBUF4/PF2)
        const unsigned short* ow = ow_bf + (size_t)i * DM * DI;
        gemm_bf16<256, 32, 4, 2, true, 2, false><<<64 * 6, 256, 0, stream>>>(
            ybf, DI, ow, DI, nullptr, xbf, DM, 64, DM, DI, nullptr, nullptr);
    }

    ln_k<<<ROWS, 256, 0, stream>>>(xbf, norm_w, norm_b, xlnbf);
    // logits: out = xlnbf @ emb^T  (empirical optimum of this family:
    // 128-tile, dual-barrier NBUF2/PF1, NT transposed epilogue; 255 us)
    gemm_bf16<256, 128, 2, 1, false, 0, true><<<393 * 16, 256, 0, stream>>>(
        xlnbf, DM, emb_bf, DM, out, nullptr, VOCAB, 16, VOCAB, DM, nullptr, nullptr);
}